// Round 12
// baseline (207.246 us; speedup 1.0000x reference)
//
#include <hip/hip_runtime.h>
#include <hip/hip_bf16.h>
#include <math.h>

#define CDIV(a,b) (((a)+(b)-1)/(b))
#define WPCV 8    // workgroups per cell for conv (64*8 = 512 blocks)
#define QPW 8     // queries per wave in knn scan
#define KC4 4     // point chunks in knn scan (wave scans N/KC4 points)

typedef __attribute__((ext_vector_type(8))) short bf16x8;
typedef __attribute__((ext_vector_type(4))) float f32x4;

__device__ __forceinline__ float elu_f(float x){ return x > 0.f ? x : expm1f(x); }
__device__ __forceinline__ unsigned short f2bf(float x){
    __hip_bfloat16 h = __float2bfloat16(x);
    union { __hip_bfloat16 b; unsigned short u; } cv; cv.b = h; return cv.u;
}
__device__ __forceinline__ float bf2f(unsigned short u){
    unsigned int ui = ((unsigned int)u) << 16;
    union { unsigned int u; float f; } cv; cv.u = ui; return cv.f;
}

// ---------------- fused: basis/hist/deg/rank + pos_x preprocess + x->bf16 ----------------
__global__ void k_basis_px(const float* __restrict__ ea, const int* __restrict__ dst,
                        float* __restrict__ basis, int* __restrict__ cellid,
                        int* __restrict__ cellcnt, int* __restrict__ deg,
                        int* __restrict__ rank, int E, int EB, int PB,
                        const float* __restrict__ posx, const int* __restrict__ bx,
                        float4* __restrict__ px4, int N,
                        const float* __restrict__ x, unsigned short* __restrict__ xbf)
{
    const int tid = threadIdx.x;
    const int bid = blockIdx.x;
    if (bid >= EB) {
        int r = bid - EB;
        if (r < PB) {                      // ---- px part ----
            int n = r*256 + tid;
            if (n < N) {
                float off = (float)bx[n] * 1e5f;
                float a = posx[n*3+0]+off, b = posx[n*3+1]+off, c = posx[n*3+2]+off;
                px4[n] = make_float4(a, b, c, a*a + b*b + c*c);
            }
        } else {                           // ---- x -> bf16 (8 elems/thread) ----
            int i = (r - PB)*256 + tid;
            if (i < N*8) {
                const float4* xs = (const float4*)x + (size_t)i*2;
                float4 a4 = xs[0], b4 = xs[1];
                bf16x8 v;
                v[0]=(short)f2bf(a4.x); v[1]=(short)f2bf(a4.y);
                v[2]=(short)f2bf(a4.z); v[3]=(short)f2bf(a4.w);
                v[4]=(short)f2bf(b4.x); v[5]=(short)f2bf(b4.y);
                v[6]=(short)f2bf(b4.z); v[7]=(short)f2bf(b4.w);
                *(bf16x8*)(xbf + (size_t)i*8) = v;
            }
        }
        return;
    }
    // ---- basis part ----
    __shared__ int hist[64];
    if (tid < 64) hist[tid] = 0;
    __syncthreads();
    int e = bid * 256 + tid;
    if (e < E) {
        float f[3]; int bi[3];
        #pragma unroll
        for (int d = 0; d < 3; d++) {
            float v = ea[e*3+d] * 4.f;      // K-1 = 4
            float b = floorf(v);
            f[d] = v - b;
            int bb = (int)b; bb = bb < 0 ? 0 : (bb > 3 ? 3 : bb);
            bi[d] = bb;
        }
        int cell = bi[0] + 4*bi[1] + 16*bi[2];
        cellid[e] = cell;
        atomicAdd(&hist[cell], 1);
        rank[e] = atomicAdd(deg + dst[e], 1);
        float bs[8];
        #pragma unroll
        for (int c = 0; c < 8; c++) {
            float b = 1.f;
            #pragma unroll
            for (int d = 0; d < 3; d++)
                b *= ((c>>d)&1) ? f[d] : (1.f - f[d]);
            bs[c] = b;
        }
        float4* bw = (float4*)(basis + (size_t)e*8);
        bw[0] = make_float4(bs[0],bs[1],bs[2],bs[3]);
        bw[1] = make_float4(bs[4],bs[5],bs[6],bs[7]);
    }
    __syncthreads();
    if (tid < 64 && hist[tid]) atomicAdd(cellcnt + tid, hist[tid]);
}

// ---------------- degree prefix scan (one block) + invdeg + cell scan ----------------
__global__ __launch_bounds__(1024) void k_degscan(const int* __restrict__ deg,
                        int* __restrict__ csr, float* __restrict__ invdeg, int N,
                        const int* __restrict__ cellcnt, int* __restrict__ cellstart,
                        int* __restrict__ cellfill)
{
    __shared__ int buf[2][1024];
    const int t = threadIdx.x;
    if (t < 64) {                          // 64-cell prefix scan in wave 0
        int v = cellcnt[t];
        int s = v;
        #pragma unroll
        for (int off = 1; off < 64; off <<= 1) {
            int o = __shfl_up(s, off, 64);
            if (t >= off) s += o;
        }
        cellstart[t] = s - v; cellfill[t] = s - v;
        if (t == 63) cellstart[64] = s;
    }
    const int base = t*8;
    int loc[8]; int s = 0;
    #pragma unroll
    for (int j = 0; j < 8; j++) {
        loc[j] = s;
        int d = (base+j < N) ? deg[base+j] : 0;
        if (base+j < N) invdeg[base+j] = 1.f / fmaxf((float)d, 1.f);
        s += d;
    }
    buf[0][t] = s; __syncthreads();
    int pb = 0;
    for (int off = 1; off < 1024; off <<= 1) {
        int v = buf[pb][t];
        if (t >= off) v += buf[pb][t-off];
        buf[pb^1][t] = v; __syncthreads(); pb ^= 1;
    }
    int excl = buf[pb][t] - s;
    #pragma unroll
    for (int j = 0; j < 8; j++)
        if (base+j < N) csr[base+j] = excl + loc[j];
    if (t == 0) csr[N] = buf[pb][1023];
}

// ---------------- fused: scatter + dstpos + wprep ----------------
__global__ __launch_bounds__(256) void k_pack(
    const int* __restrict__ cellid, int* __restrict__ fill, int* __restrict__ elist,
    const int* __restrict__ dst, const int* __restrict__ rank,
    const int* __restrict__ csr, int* __restrict__ dstpos, int E, int SB,
    const float* __restrict__ Wa, const float* __restrict__ Wb,
    unsigned short* __restrict__ WTa, unsigned short* __restrict__ WTb)
{
    __shared__ float shbuf[64*65];
    const int tid = threadIdx.x;
    const int bid = blockIdx.x;
    if (bid < SB) {                        // ---- scatter ----
        int* hist = (int*)shbuf;
        int* bas  = hist + 64;
        if (tid < 64) hist[tid] = 0;
        __syncthreads();
        int e = bid * 256 + tid;
        int cell = 0, loc = 0;
        bool act = e < E;
        if (act) { cell = cellid[e]; loc = atomicAdd(&hist[cell], 1); }
        __syncthreads();
        if (tid < 64) bas[tid] = hist[tid] ? atomicAdd(fill + tid, hist[tid]) : 0;
        __syncthreads();
        if (act) elist[bas[cell] + loc] = e;
    } else if (bid < 2*SB) {               // ---- dstpos: e -> slot in dst-sorted order ----
        int e = (bid - SB) * 256 + tid;
        if (e < E) dstpos[e] = csr[dst[e]] + rank[e];
    } else {                               // ---- wprep ----
        int b = bid - 2*SB;
        float (*ws65)[65] = (float(*)[65])shbuf;
        const float* Wsrc = (b < 125) ? (Wa + (size_t)b*4096) : (Wb + (size_t)(b-125)*4096);
        unsigned short* Wdst = (b < 125) ? (WTa + (size_t)b*4096) : (WTb + (size_t)(b-125)*4096);
        #pragma unroll
        for (int j = 0; j < 16; j++) {
            int idx = j*256 + tid;             // idx = i*64 + o
            ws65[idx>>6][idx&63] = Wsrc[idx];
        }
        __syncthreads();
        #pragma unroll
        for (int j = 0; j < 16; j++) {
            int idx = j*256 + tid;             // idx = o*64 + i
            int o = idx>>6, i = idx&63;
            Wdst[idx] = f2bf(ws65[i][o]);
        }
    }
}

// ---------------- spline conv: MFMA, W8 in LDS, bf16 input, ye dst-sorted ----------------
__global__ __launch_bounds__(256) void k_conv(
    const unsigned short* __restrict__ xin, const unsigned short* __restrict__ WT,
    const int* __restrict__ elist, const int* __restrict__ cellstart,
    const float* __restrict__ basis, const int* __restrict__ src,
    const int* __restrict__ dstpos, unsigned short* __restrict__ ye)
{
    __shared__ unsigned short wt[8][64][64];   // [corner][out][in] bf16, row-swizzled
    __shared__ unsigned short xb[64][64];      // [edge][in] bf16, row-swizzled
    __shared__ float bts[8][64];               // [corner][edge]
    __shared__ int dpos[64];

    const int cell = blockIdx.x / WPCV;
    const int sub  = blockIdx.x % WPCV;
    const int tid  = threadIdx.x;
    const int w    = tid >> 6;
    const int lane = tid & 63;
    const int eh   = w >> 1;       // edge half (0/1)
    const int oh   = w & 1;        // out half (0/1)
    const int l15  = lane & 15;
    const int kgrp = lane >> 4;    // 0..3
    const int swz  = lane & 7;

    int kc[8];
    {
        int b0 = cell & 3, b1 = (cell >> 2) & 3, b2 = (cell >> 4) & 3;
        #pragma unroll
        for (int c = 0; c < 8; c++)
            kc[c] = (b0 + (c&1)) + 5*(b1 + ((c>>1)&1)) + 25*(b2 + ((c>>2)&1));
    }

    #pragma unroll
    for (int j = 0; j < 16; j++) {
        int cj  = j >> 1;
        int off = ((j & 1) << 8) + tid;
        int row = off >> 3, colc = off & 7;
        bf16x8 v = ((const bf16x8*)(WT + (size_t)kc[cj]*4096))[off];
        *(bf16x8*)&wt[cj][row][(colc ^ (row & 7)) << 3] = v;
    }

    const int s0 = cellstart[cell], s1 = cellstart[cell+1];
    const int se = tid >> 2, sm = tid & 3;

    for (int base = s0 + sub*64; base < s1; base += WPCV*64) {
        int ne = s1 - base; ne = ne > 64 ? 64 : ne;
        __syncthreads();
        int c0 = (sm*2)     ^ (se & 7);
        int c1 = (sm*2 + 1) ^ (se & 7);
        if (se < ne) {
            int eid = elist[base + se];
            int sn  = src[eid];
            const bf16x8* xr = (const bf16x8*)(xin + (size_t)sn*64);
            bf16x8 v0 = xr[sm*2], v1 = xr[sm*2+1];
            *(bf16x8*)&xb[se][c0 << 3] = v0;
            *(bf16x8*)&xb[se][c1 << 3] = v1;
            if (sm == 0) {
                const float4* br = (const float4*)(basis + (size_t)eid*8);
                float4 bA = br[0], bB = br[1];
                bts[0][se]=bA.x; bts[1][se]=bA.y; bts[2][se]=bA.z; bts[3][se]=bA.w;
                bts[4][se]=bB.x; bts[5][se]=bB.y; bts[6][se]=bB.z; bts[7][se]=bB.w;
                dpos[se] = dstpos[eid];
            }
        } else {
            bf16x8 z = {0,0,0,0,0,0,0,0};
            *(bf16x8*)&xb[se][c0 << 3] = z;
            *(bf16x8*)&xb[se][c1 << 3] = z;
            if (sm == 0) dpos[se] = -1;
        }
        __syncthreads();

        bf16x8 a[2][2];
        #pragma unroll
        for (int me = 0; me < 2; me++) {
            int arow = eh*32 + me*16 + l15;
            #pragma unroll
            for (int kh = 0; kh < 2; kh++)
                a[me][kh] = *(const bf16x8*)&xb[arow][((kh*4 + kgrp) ^ swz) << 3];
        }

        f32x4 y[2][2] = {{{0,0,0,0},{0,0,0,0}},{{0,0,0,0},{0,0,0,0}}};
        #pragma unroll
        for (int c = 0; c < 8; c++) {
            float4 bv[2];
            bv[0] = *(const float4*)&bts[c][eh*32 +      (kgrp << 2)];
            bv[1] = *(const float4*)&bts[c][eh*32 + 16 + (kgrp << 2)];
            bf16x8 bfr[2][2];
            #pragma unroll
            for (int nb = 0; nb < 2; nb++) {
                int brow = oh*32 + nb*16 + l15;
                #pragma unroll
                for (int kh = 0; kh < 2; kh++)
                    bfr[nb][kh] = *(const bf16x8*)&wt[c][brow][((kh*4 + kgrp) ^ swz) << 3];
            }
            #pragma unroll
            for (int me = 0; me < 2; me++) {
                #pragma unroll
                for (int nb = 0; nb < 2; nb++) {
                    f32x4 t = {0.f, 0.f, 0.f, 0.f};
                    t = __builtin_amdgcn_mfma_f32_16x16x32_bf16(a[me][0], bfr[nb][0], t, 0, 0, 0);
                    t = __builtin_amdgcn_mfma_f32_16x16x32_bf16(a[me][1], bfr[nb][1], t, 0, 0, 0);
                    y[me][nb][0] = fmaf(bv[me].x, t[0], y[me][nb][0]);
                    y[me][nb][1] = fmaf(bv[me].y, t[1], y[me][nb][1]);
                    y[me][nb][2] = fmaf(bv[me].z, t[2], y[me][nb][2]);
                    y[me][nb][3] = fmaf(bv[me].w, t[3], y[me][nb][3]);
                }
            }
        }
        #pragma unroll
        for (int me = 0; me < 2; me++) {
            #pragma unroll
            for (int r = 0; r < 4; r++) {
                int el = eh*32 + me*16 + (kgrp << 2) + r;
                int dp = dpos[el];
                if (dp >= 0) {
                    unsigned short* yp = ye + (size_t)dp*64 + oh*32 + l15;
                    yp[0]  = f2bf(y[me][0][r]);
                    yp[16] = f2bf(y[me][1][r]);
                }
            }
        }
    }
}

// ---------------- gather by dst: sequential ye rows, bf16 in/out ----------------
__global__ __launch_bounds__(256) void k_gather(
    const unsigned short* __restrict__ ye, const int* __restrict__ csr,
    const unsigned short* __restrict__ xin, const float* __restrict__ root,
    const float* __restrict__ bias, const float* __restrict__ invdeg,
    unsigned short* __restrict__ hout, int N)
{
    __shared__ float sh[4][64];
    const int w = threadIdx.x >> 6, lane = threadIdx.x & 63;
    const int n = blockIdx.x*4 + w;
    if (n >= N) return;
    const int s0 = csr[n], s1 = csr[n+1];
    const int j8 = lane >> 3, c8 = lane & 7;
    float acc[8] = {};
    for (int base = s0; base < s1; base += 8) {
        int ei = base + j8;
        if (ei < s1) {
            bf16x8 v = *(const bf16x8*)(ye + (size_t)ei*64 + c8*8);
            #pragma unroll
            for (int k = 0; k < 8; k++)
                acc[k] += bf2f((unsigned short)v[k]);
        }
    }
    #pragma unroll
    for (int m = 8; m <= 32; m <<= 1) {
        #pragma unroll
        for (int k = 0; k < 8; k++)
            acc[k] += __shfl_xor(acc[k], m, 64);
    }
    if (j8 == 0) {
        #pragma unroll
        for (int k = 0; k < 8; k++) sh[w][c8*8+k] = acc[k];
    }
    float aggr = sh[w][lane];            // same-wave LDS write->read
    float av = aggr * invdeg[n];
    float xv = bf2f(xin[(size_t)n*64 + lane]);
    float rt = bias[lane];
    #pragma unroll 8
    for (int i = 0; i < 64; i++)
        rt = fmaf(__shfl(xv, i, 64), root[i*64 + lane], rt);
    hout[(size_t)n*64 + lane] = f2bf(elu_f(av + rt));
}

// ---------------- 3-NN scan: wave=8 queries, lanes=points, ballot-pruned, chunked ----------------
// grid = (Ny/(QPW*4)) * KC4 blocks; block's 4 waves share chunk ch, each owns 8 queries.
__global__ __launch_bounds__(256) void k_knn_scan(
    const float4* __restrict__ px4, const float* __restrict__ posy,
    const int* __restrict__ by, float* __restrict__ pd, int* __restrict__ pi,
    int N, int Ny)
{
    const int bq   = blockIdx.x / KC4;
    const int ch   = blockIdx.x % KC4;
    const int lane = threadIdx.x & 63;
    const int qbase = (bq*4 + (threadIdx.x >> 6)) * QPW;
    const int NC   = N / KC4;              // 2048
    const int pbase = ch * NC;

    int ql = qbase + (lane & (QPW-1));
    float offv = (float)by[ql] * 1e5f;
    float qa = posy[ql*3+0]+offv, qb = posy[ql*3+1]+offv, qc = posy[ql*3+2]+offv;
    float sy_l  = qa*qa + qb*qb + qc*qc;
    float a2_l = -2.f*qa, b2_l = -2.f*qb, c2_l = -2.f*qc;

    float SY[QPW], A2[QPW], B2[QPW], C2[QPW];
    float d0[QPW], d1[QPW], d2s[QPW];
    int   i0[QPW], i1[QPW], i2[QPW];
    #pragma unroll
    for (int g = 0; g < QPW; g++) {
        SY[g] = __shfl(sy_l, g);
        A2[g] = __shfl(a2_l, g);
        B2[g] = __shfl(b2_l, g);
        C2[g] = __shfl(c2_l, g);
    }

    // warm start: exact top-3 of the chunk's first 64 points (butterfly w/ index tie-break)
    {
        float4 p0 = px4[pbase + lane];
        #pragma unroll
        for (int g = 0; g < QPW; g++) {
            float uu = fmaf(A2[g], p0.x, fmaf(B2[g], p0.y, fmaf(C2[g], p0.z, SY[g] + p0.w)));
            #pragma unroll
            for (int j = 0; j < 3; j++) {
                float md = uu; int mi = pbase + lane;
                #pragma unroll
                for (int s = 1; s < 64; s <<= 1) {
                    float od = __shfl_xor(md, s, 64);
                    int   oi = __shfl_xor(mi, s, 64);
                    if (od < md || (od == md && oi < mi)) { md = od; mi = oi; }
                }
                if (j == 0) { d0[g] = md; i0[g] = mi; }
                else if (j == 1) { d1[g] = md; i1[g] = mi; }
                else { d2s[g] = md; i2[g] = mi; }
                if (pbase + lane == mi) uu = 3.4e38f;
            }
        }
    }

    // main scan: ballot-pruned exact insert (ascending index order)
    const int nb = NC >> 6;                // 32 batches
    float4 cur = px4[pbase + 64 + lane];
    for (int b = 1; b < nb; b++) {
        float4 nxt;
        if (b + 1 < nb) nxt = px4[(size_t)pbase + ((b+1) << 6) + lane];
        const int gb = pbase + (b << 6);
        #pragma unroll
        for (int g = 0; g < QPW; g++) {
            float u = fmaf(A2[g], cur.x, fmaf(B2[g], cur.y, fmaf(C2[g], cur.z, SY[g] + cur.w)));
            unsigned long long m = __ballot(u < d2s[g]);
            while (m) {
                int l = __builtin_ctzll(m);
                m &= m - 1;
                float uc = __shfl(u, l);
                int   ic = gb + l;
                bool c0 = uc < d0[g], c1 = uc < d1[g], c2 = uc < d2s[g];
                float Md  = c0 ? d0[g] : uc;  int Mi  = c0 ? i0[g] : ic;
                float Md1 = c1 ? d1[g] : Md;  int Mi1 = c1 ? i1[g] : Mi;
                d2s[g] = c2 ? Md1 : d2s[g];   i2[g] = c2 ? Mi1 : i2[g];
                d1[g]  = c1 ? Md  : d1[g];    i1[g] = c1 ? Mi  : i1[g];
                d0[g]  = c0 ? uc  : d0[g];    i0[g] = c0 ? ic  : i0[g];
            }
        }
        cur = nxt;
    }

    // write partial top-3 (values wave-uniform); layout [ch][q][3]
    #pragma unroll
    for (int g = 0; g < QPW; g++) {
        if (lane == g) {
            size_t ob = ((size_t)ch*Ny + qbase + g)*3;
            pd[ob+0]=d0[g]; pd[ob+1]=d1[g]; pd[ob+2]=d2s[g];
            pi[ob+0]=i0[g]; pi[ob+1]=i1[g]; pi[ob+2]=i2[g];
        }
    }
}

// ---------------- 3-NN merge: 12 candidates + interpolate (bf16 h2) ----------------
__global__ __launch_bounds__(256) void k_knn_merge(
    const float* __restrict__ pd, const int* __restrict__ pi,
    const unsigned short* __restrict__ h2, float* __restrict__ out, int Ny)
{
    const int w = threadIdx.x >> 6, lane = threadIdx.x & 63;
    const int q = blockIdx.x*4 + w;
    float a0 = 3.4e38f; int b0 = 0x7fffffff;
    if (lane < KC4*3) {
        size_t base = ((size_t)(lane/3)*Ny + q)*3 + (lane%3);
        a0 = pd[base]; b0 = pi[base];
    }
    float rd[3]; int ri[3];
    #pragma unroll
    for (int j = 0; j < 3; j++) {
        float md = a0; int mi = b0;
        #pragma unroll
        for (int s = 1; s < 64; s <<= 1) {
            float od = __shfl_xor(md, s, 64);
            int   oi = __shfl_xor(mi, s, 64);
            if (od < md || (od == md && oi < mi)) { md = od; mi = oi; }
        }
        rd[j] = md; ri[j] = mi;
        if (b0 == mi) { a0 = 3.4e38f; b0 = 0x7fffffff; }
    }
    float w0 = 1.f/fmaxf(rd[0], 1e-16f);
    float w1 = 1.f/fmaxf(rd[1], 1e-16f);
    float w2 = 1.f/fmaxf(rd[2], 1e-16f);
    float ws = w0 + w1 + w2;
    float v = w0*bf2f(h2[(size_t)ri[0]*64+lane]) + w1*bf2f(h2[(size_t)ri[1]*64+lane])
            + w2*bf2f(h2[(size_t)ri[2]*64+lane]);
    out[(size_t)q*64+lane] = v / ws;
}

extern "C" void kernel_launch(void* const* d_in, const int* in_sizes, int n_in,
                              void* d_out, int out_size, void* d_ws, size_t ws_size,
                              hipStream_t stream)
{
    const float* x     = (const float*)d_in[0];
    const int*   ei    = (const int*)d_in[1];
    const float* ea    = (const float*)d_in[2];
    const float* posx  = (const float*)d_in[3];
    const int*   bx    = (const int*)d_in[4];
    const float* posy  = (const float*)d_in[5];
    const int*   by    = (const int*)d_in[6];
    const float* Wa    = (const float*)d_in[7];
    const float* roota = (const float*)d_in[8];
    const float* biasa = (const float*)d_in[9];
    const float* Wb    = (const float*)d_in[10];
    const float* rootb = (const float*)d_in[11];
    const float* biasb = (const float*)d_in[12];

    const int N  = in_sizes[0] / 64;
    const int E  = in_sizes[1] / 2;
    const int Ny = in_sizes[5] / 3;
    const int* srcp = ei;
    const int* dstp = ei + E;

    char* ws = (char*)d_ws;
    size_t off = 0;
    auto alloc = [&](size_t bytes) { void* p = ws + off; off += (bytes + 255) & ~255ull; return p; };
    float*  basis    = (float*)alloc((size_t)E*8*4);
    int*    cellid   = (int*)  alloc((size_t)E*4);
    int*    rank     = (int*)  alloc((size_t)E*4);
    int*    elist    = (int*)  alloc((size_t)E*4);
    int*    dstpos   = (int*)  alloc((size_t)E*4);
    int*    deg      = (int*)  alloc((size_t)N*4);     // deg + cellcnt contiguous: one memset
    int*    cellcnt  = (int*)  alloc(64*4);
    int*    csr      = (int*)  alloc((size_t)(N+1)*4);
    float*  invdeg   = (float*)alloc((size_t)N*4);
    int*    cellstart= (int*)  alloc(65*4);
    int*    cellfill = (int*)  alloc(64*4);
    unsigned short* xbf = (unsigned short*)alloc((size_t)N*64*2);
    unsigned short* h1  = (unsigned short*)alloc((size_t)N*64*2);
    unsigned short* h2  = (unsigned short*)alloc((size_t)N*64*2);
    float4* px4      = (float4*)alloc((size_t)N*16);
    unsigned short* WTa = (unsigned short*)alloc((size_t)125*4096*2);
    unsigned short* WTb = (unsigned short*)alloc((size_t)125*4096*2);
    unsigned short* ye  = (unsigned short*)alloc((size_t)E*64*2);
    // pd/pi alias ye (dead by knn time): KC4*Ny*3*4 = 786 KB each; ye is 16.8 MB
    float* pd = (float*)ye;
    int*   pi = (int*)((char*)ye + ((size_t)4<<20));
    (void)ws_size; (void)n_in; (void)out_size;

    const int EB = CDIV(E,256);        // 512
    const int PB = CDIV(N,256);        // 32
    const int XB = CDIV(N*8,256);      // 256 (x->bf16, 8 elems/thread)

    hipMemsetAsync(deg, 0, (size_t)N*4 + 256, stream);   // zeroes deg + cellcnt

    k_basis_px<<<EB+PB+XB, 256, 0, stream>>>(ea, dstp, basis, cellid, cellcnt, deg, rank,
                                             E, EB, PB, posx, bx, px4, N, x, xbf);
    k_degscan <<<1, 1024, 0, stream>>>(deg, csr, invdeg, N, cellcnt, cellstart, cellfill);
    k_pack    <<<2*EB + 250, 256, 0, stream>>>(cellid, cellfill, elist, dstp, rank,
                                               csr, dstpos, E, EB, Wa, Wb, WTa, WTb);

    k_conv  <<<64*WPCV, 256, 0, stream>>>(xbf, WTa, elist, cellstart, basis, srcp, dstpos, ye);
    k_gather<<<CDIV(N,4), 256, 0, stream>>>(ye, csr, xbf, roota, biasa, invdeg, h1, N);

    k_conv  <<<64*WPCV, 256, 0, stream>>>(h1, WTb, elist, cellstart, basis, srcp, dstpos, ye);
    k_gather<<<CDIV(N,4), 256, 0, stream>>>(ye, csr, h1, rootb, biasb, invdeg, h2, N);

    k_knn_scan <<<(Ny/(QPW*4))*KC4, 256, 0, stream>>>(px4, posy, by, pd, pi, N, Ny);
    k_knn_merge<<<Ny/4, 256, 0, stream>>>(pd, pi, h2, (float*)d_out, Ny);
}

// Round 13
// 195.625 us; speedup vs baseline: 1.0594x; 1.0594x over previous
//
#include <hip/hip_runtime.h>
#include <hip/hip_bf16.h>
#include <math.h>

#define CDIV(a,b) (((a)+(b)-1)/(b))
#define WPCV 8    // workgroups per cell for conv (64*8 = 512 blocks)
#define GDIM 16   // knn grid 16^3

typedef __attribute__((ext_vector_type(8))) short bf16x8;
typedef __attribute__((ext_vector_type(4))) float f32x4;

__device__ __forceinline__ float elu_f(float x){ return x > 0.f ? x : expm1f(x); }
__device__ __forceinline__ unsigned short f2bf(float x){
    __hip_bfloat16 h = __float2bfloat16(x);
    union { __hip_bfloat16 b; unsigned short u; } cv; cv.b = h; return cv.u;
}
__device__ __forceinline__ float bf2f(unsigned short u){
    unsigned int ui = ((unsigned int)u) << 16;
    union { unsigned int u; float f; } cv; cv.u = ui; return cv.f;
}
__device__ __forceinline__ unsigned int enc_key(float f){
    int i = __float_as_int(f);
    return (unsigned int)(i ^ ((i >> 31) | 0x80000000));
}
__device__ __forceinline__ float dec_key(unsigned int k){
    unsigned int u = (k & 0x80000000u) ? (k & 0x7FFFFFFFu) : ~k;
    return __uint_as_float(u);
}

// exact wave top-3 merge of per-lane sorted triples, lexicographic (d, idx)
__device__ __forceinline__ void merge3(float d0, int i0, float d1, int i1,
                                       float d2, int i2, float* rd, int* ri)
{
    #pragma unroll
    for (int j = 0; j < 3; j++) {
        float md = d0; int mi = i0;
        #pragma unroll
        for (int s = 1; s < 64; s <<= 1) {
            float od = __shfl_xor(md, s, 64);
            int   oi = __shfl_xor(mi, s, 64);
            if (od < md || (od == md && oi < mi)) { md = od; mi = oi; }
        }
        rd[j] = md; ri[j] = mi;
        if (i0 == mi) { d0 = d1; i0 = i1; d1 = d2; i1 = i2; d2 = 3.4e38f; i2 = 0x7fffffff; }
    }
}

// ---------------- fused: basis/hist/deg/rank + pos_x preprocess (+minmax) + x->bf16 ----------------
__global__ void k_basis_px(const float* __restrict__ ea, const int* __restrict__ dst,
                        float* __restrict__ basis, int* __restrict__ cellid,
                        int* __restrict__ cellcnt, int* __restrict__ deg,
                        int* __restrict__ rank, int E, int EB, int PB,
                        const float* __restrict__ posx, const int* __restrict__ bx,
                        float4* __restrict__ px4, int N,
                        const float* __restrict__ x, unsigned short* __restrict__ xbf,
                        unsigned int* __restrict__ mmin, unsigned int* __restrict__ mmax)
{
    const int tid = threadIdx.x;
    const int bid = blockIdx.x;
    if (bid >= EB) {
        int r = bid - EB;
        if (r < PB) {                      // ---- px part + bbox reduce ----
            int n = r*256 + tid;
            float a = 0.f, b = 0.f, c = 0.f;
            bool act = n < N;
            if (act) {
                float off = (float)bx[n] * 1e5f;
                a = posx[n*3+0]+off; b = posx[n*3+1]+off; c = posx[n*3+2]+off;
                px4[n] = make_float4(a, b, c, a*a + b*b + c*c);
            }
            float mn[3], mx[3];
            mn[0] = act ? a :  3.4e38f; mx[0] = act ? a : -3.4e38f;
            mn[1] = act ? b :  3.4e38f; mx[1] = act ? b : -3.4e38f;
            mn[2] = act ? c :  3.4e38f; mx[2] = act ? c : -3.4e38f;
            #pragma unroll
            for (int s = 1; s < 64; s <<= 1) {
                #pragma unroll
                for (int d = 0; d < 3; d++) {
                    mn[d] = fminf(mn[d], __shfl_xor(mn[d], s, 64));
                    mx[d] = fmaxf(mx[d], __shfl_xor(mx[d], s, 64));
                }
            }
            if ((tid & 63) == 0) {
                #pragma unroll
                for (int d = 0; d < 3; d++) {
                    atomicMin(mmin + d, enc_key(mn[d]));
                    atomicMax(mmax + d, enc_key(mx[d]));
                }
            }
        } else {                           // ---- x -> bf16 (8 elems/thread) ----
            int i = (r - PB)*256 + tid;
            if (i < N*8) {
                const float4* xs = (const float4*)x + (size_t)i*2;
                float4 a4 = xs[0], b4 = xs[1];
                bf16x8 v;
                v[0]=(short)f2bf(a4.x); v[1]=(short)f2bf(a4.y);
                v[2]=(short)f2bf(a4.z); v[3]=(short)f2bf(a4.w);
                v[4]=(short)f2bf(b4.x); v[5]=(short)f2bf(b4.y);
                v[6]=(short)f2bf(b4.z); v[7]=(short)f2bf(b4.w);
                *(bf16x8*)(xbf + (size_t)i*8) = v;
            }
        }
        return;
    }
    // ---- basis part ----
    __shared__ int hist[64];
    if (tid < 64) hist[tid] = 0;
    __syncthreads();
    int e = bid * 256 + tid;
    if (e < E) {
        float f[3]; int bi[3];
        #pragma unroll
        for (int d = 0; d < 3; d++) {
            float v = ea[e*3+d] * 4.f;      // K-1 = 4
            float b = floorf(v);
            f[d] = v - b;
            int bb = (int)b; bb = bb < 0 ? 0 : (bb > 3 ? 3 : bb);
            bi[d] = bb;
        }
        int cell = bi[0] + 4*bi[1] + 16*bi[2];
        cellid[e] = cell;
        atomicAdd(&hist[cell], 1);
        rank[e] = atomicAdd(deg + dst[e], 1);
        float bs[8];
        #pragma unroll
        for (int c = 0; c < 8; c++) {
            float b = 1.f;
            #pragma unroll
            for (int d = 0; d < 3; d++)
                b *= ((c>>d)&1) ? f[d] : (1.f - f[d]);
            bs[c] = b;
        }
        float4* bw = (float4*)(basis + (size_t)e*8);
        bw[0] = make_float4(bs[0],bs[1],bs[2],bs[3]);
        bw[1] = make_float4(bs[4],bs[5],bs[6],bs[7]);
    }
    __syncthreads();
    if (tid < 64 && hist[tid]) atomicAdd(cellcnt + tid, hist[tid]);
}

// ---------------- degree scan + invdeg + cell64 scan + knn-grid histogram/scan ----------------
__global__ __launch_bounds__(1024) void k_degscan(const int* __restrict__ deg,
                        int* __restrict__ csr, float* __restrict__ invdeg, int N,
                        const int* __restrict__ cellcnt, int* __restrict__ cellstart,
                        int* __restrict__ cellfill,
                        const float4* __restrict__ px4,
                        const unsigned int* __restrict__ mmin,
                        const unsigned int* __restrict__ mmax,
                        int* __restrict__ gstart, int* __restrict__ gfill,
                        float* __restrict__ gmeta)
{
    __shared__ int buf[2][1024];
    __shared__ int ghist[GDIM*GDIM*GDIM];
    const int t = threadIdx.x;
    if (t < 64) {                          // 64-cell prefix scan in wave 0
        int v = cellcnt[t];
        int s = v;
        #pragma unroll
        for (int off = 1; off < 64; off <<= 1) {
            int o = __shfl_up(s, off, 64);
            if (t >= off) s += o;
        }
        cellstart[t] = s - v; cellfill[t] = s - v;
        if (t == 63) cellstart[64] = s;
    }
    #pragma unroll
    for (int j = 0; j < 4; j++) ghist[t*4+j] = 0;
    // decode bbox, compute grid meta
    float lov[3], wv[3], iwv[3];
    #pragma unroll
    for (int d = 0; d < 3; d++) {
        float flo = dec_key(mmin[d]);
        float fhi = dec_key(mmax[d]);
        lov[d] = flo;
        wv[d]  = (fhi - flo) / (float)GDIM;
        iwv[d] = wv[d] > 0.f ? 1.f / wv[d] : 0.f;
    }
    if (t == 0) {
        gmeta[0]=lov[0]; gmeta[1]=lov[1]; gmeta[2]=lov[2];
        gmeta[3]=wv[0];  gmeta[4]=wv[1];  gmeta[5]=wv[2];
        gmeta[6]=iwv[0]; gmeta[7]=iwv[1]; gmeta[8]=iwv[2];
    }
    __syncthreads();
    // histogram points into grid cells
    #pragma unroll
    for (int j = 0; j < 8; j++) {
        int n = t*8 + j;
        if (n < N) {
            float4 p = px4[n];
            int cx = (int)((p.x - lov[0]) * iwv[0]); cx = cx < 0 ? 0 : (cx > GDIM-1 ? GDIM-1 : cx);
            int cy = (int)((p.y - lov[1]) * iwv[1]); cy = cy < 0 ? 0 : (cy > GDIM-1 ? GDIM-1 : cy);
            int cz = (int)((p.z - lov[2]) * iwv[2]); cz = cz < 0 ? 0 : (cz > GDIM-1 ? GDIM-1 : cz);
            atomicAdd(&ghist[cx + (cy<<4) + (cz<<8)], 1);
        }
    }
    // degree scan
    const int base = t*8;
    int loc[8]; int s = 0;
    #pragma unroll
    for (int j = 0; j < 8; j++) {
        loc[j] = s;
        int d = (base+j < N) ? deg[base+j] : 0;
        if (base+j < N) invdeg[base+j] = 1.f / fmaxf((float)d, 1.f);
        s += d;
    }
    buf[0][t] = s; __syncthreads();
    int pb = 0;
    for (int off = 1; off < 1024; off <<= 1) {
        int v = buf[pb][t];
        if (t >= off) v += buf[pb][t-off];
        buf[pb^1][t] = v; __syncthreads(); pb ^= 1;
    }
    int excl = buf[pb][t] - s;
    #pragma unroll
    for (int j = 0; j < 8; j++)
        if (base+j < N) csr[base+j] = excl + loc[j];
    if (t == 0) csr[N] = buf[pb][1023];
    __syncthreads();
    // grid-cell scan (4096 cells, 4 per thread)
    int gl[4]; int gs = 0;
    #pragma unroll
    for (int j = 0; j < 4; j++) { gl[j] = gs; gs += ghist[t*4+j]; }
    buf[0][t] = gs; __syncthreads();
    pb = 0;
    for (int off = 1; off < 1024; off <<= 1) {
        int v = buf[pb][t];
        if (t >= off) v += buf[pb][t-off];
        buf[pb^1][t] = v; __syncthreads(); pb ^= 1;
    }
    int gex = buf[pb][t] - gs;
    #pragma unroll
    for (int j = 0; j < 4; j++) {
        gstart[t*4+j] = gex + gl[j];
        gfill [t*4+j] = gex + gl[j];
    }
    if (t == 1023) gstart[4096] = buf[pb][1023];
}

// ---------------- fused: scatter + dstpos + wprep + knn point scatter ----------------
__global__ __launch_bounds__(256) void k_pack(
    const int* __restrict__ cellid, int* __restrict__ fill, int* __restrict__ elist,
    const int* __restrict__ dst, const int* __restrict__ rank,
    const int* __restrict__ csr, int* __restrict__ dstpos, int E, int SB,
    const float* __restrict__ Wa, const float* __restrict__ Wb,
    unsigned short* __restrict__ WTa, unsigned short* __restrict__ WTb,
    const float4* __restrict__ px4, const float* __restrict__ gmeta,
    int* __restrict__ gfill, float4* __restrict__ pxg, int* __restrict__ gidx, int N)
{
    __shared__ float shbuf[64*65];
    const int tid = threadIdx.x;
    const int bid = blockIdx.x;
    if (bid < SB) {                        // ---- scatter edges by cell ----
        int* hist = (int*)shbuf;
        int* bas  = hist + 64;
        if (tid < 64) hist[tid] = 0;
        __syncthreads();
        int e = bid * 256 + tid;
        int cell = 0, loc = 0;
        bool act = e < E;
        if (act) { cell = cellid[e]; loc = atomicAdd(&hist[cell], 1); }
        __syncthreads();
        if (tid < 64) bas[tid] = hist[tid] ? atomicAdd(fill + tid, hist[tid]) : 0;
        __syncthreads();
        if (act) elist[bas[cell] + loc] = e;
    } else if (bid < 2*SB) {               // ---- dstpos ----
        int e = (bid - SB) * 256 + tid;
        if (e < E) dstpos[e] = csr[dst[e]] + rank[e];
    } else if (bid < 2*SB + 250) {         // ---- wprep ----
        int b = bid - 2*SB;
        float (*ws65)[65] = (float(*)[65])shbuf;
        const float* Wsrc = (b < 125) ? (Wa + (size_t)b*4096) : (Wb + (size_t)(b-125)*4096);
        unsigned short* Wdst = (b < 125) ? (WTa + (size_t)b*4096) : (WTb + (size_t)(b-125)*4096);
        #pragma unroll
        for (int j = 0; j < 16; j++) {
            int idx = j*256 + tid;             // idx = i*64 + o
            ws65[idx>>6][idx&63] = Wsrc[idx];
        }
        __syncthreads();
        #pragma unroll
        for (int j = 0; j < 16; j++) {
            int idx = j*256 + tid;             // idx = o*64 + i
            int o = idx>>6, i = idx&63;
            Wdst[idx] = f2bf(ws65[i][o]);
        }
    } else {                               // ---- knn point scatter ----
        int n = (bid - (2*SB + 250))*256 + tid;
        if (n < N) {
            float lo0 = gmeta[0], lo1 = gmeta[1], lo2 = gmeta[2];
            float iw0 = gmeta[6], iw1 = gmeta[7], iw2 = gmeta[8];
            float4 p = px4[n];
            int cx = (int)((p.x - lo0) * iw0); cx = cx < 0 ? 0 : (cx > GDIM-1 ? GDIM-1 : cx);
            int cy = (int)((p.y - lo1) * iw1); cy = cy < 0 ? 0 : (cy > GDIM-1 ? GDIM-1 : cy);
            int cz = (int)((p.z - lo2) * iw2); cz = cz < 0 ? 0 : (cz > GDIM-1 ? GDIM-1 : cz);
            int slot = atomicAdd(gfill + (cx + (cy<<4) + (cz<<8)), 1);
            pxg[slot] = p;
            gidx[slot] = n;
        }
    }
}

// ---------------- spline conv: MFMA, W8 in LDS, bf16 input, ye dst-sorted ----------------
__global__ __launch_bounds__(256) void k_conv(
    const unsigned short* __restrict__ xin, const unsigned short* __restrict__ WT,
    const int* __restrict__ elist, const int* __restrict__ cellstart,
    const float* __restrict__ basis, const int* __restrict__ src,
    const int* __restrict__ dstpos, unsigned short* __restrict__ ye)
{
    __shared__ unsigned short wt[8][64][64];   // [corner][out][in] bf16, row-swizzled
    __shared__ unsigned short xb[64][64];      // [edge][in] bf16, row-swizzled
    __shared__ float bts[8][64];               // [corner][edge]
    __shared__ int dpos[64];

    const int cell = blockIdx.x / WPCV;
    const int sub  = blockIdx.x % WPCV;
    const int tid  = threadIdx.x;
    const int w    = tid >> 6;
    const int lane = tid & 63;
    const int eh   = w >> 1;       // edge half (0/1)
    const int oh   = w & 1;        // out half (0/1)
    const int l15  = lane & 15;
    const int kgrp = lane >> 4;    // 0..3
    const int swz  = lane & 7;

    int kc[8];
    {
        int b0 = cell & 3, b1 = (cell >> 2) & 3, b2 = (cell >> 4) & 3;
        #pragma unroll
        for (int c = 0; c < 8; c++)
            kc[c] = (b0 + (c&1)) + 5*(b1 + ((c>>1)&1)) + 25*(b2 + ((c>>2)&1));
    }

    #pragma unroll
    for (int j = 0; j < 16; j++) {
        int cj  = j >> 1;
        int off = ((j & 1) << 8) + tid;
        int row = off >> 3, colc = off & 7;
        bf16x8 v = ((const bf16x8*)(WT + (size_t)kc[cj]*4096))[off];
        *(bf16x8*)&wt[cj][row][(colc ^ (row & 7)) << 3] = v;
    }

    const int s0 = cellstart[cell], s1 = cellstart[cell+1];
    const int se = tid >> 2, sm = tid & 3;

    for (int base = s0 + sub*64; base < s1; base += WPCV*64) {
        int ne = s1 - base; ne = ne > 64 ? 64 : ne;
        __syncthreads();
        int c0 = (sm*2)     ^ (se & 7);
        int c1 = (sm*2 + 1) ^ (se & 7);
        if (se < ne) {
            int eid = elist[base + se];
            int sn  = src[eid];
            const bf16x8* xr = (const bf16x8*)(xin + (size_t)sn*64);
            bf16x8 v0 = xr[sm*2], v1 = xr[sm*2+1];
            *(bf16x8*)&xb[se][c0 << 3] = v0;
            *(bf16x8*)&xb[se][c1 << 3] = v1;
            if (sm == 0) {
                const float4* br = (const float4*)(basis + (size_t)eid*8);
                float4 bA = br[0], bB = br[1];
                bts[0][se]=bA.x; bts[1][se]=bA.y; bts[2][se]=bA.z; bts[3][se]=bA.w;
                bts[4][se]=bB.x; bts[5][se]=bB.y; bts[6][se]=bB.z; bts[7][se]=bB.w;
                dpos[se] = dstpos[eid];
            }
        } else {
            bf16x8 z = {0,0,0,0,0,0,0,0};
            *(bf16x8*)&xb[se][c0 << 3] = z;
            *(bf16x8*)&xb[se][c1 << 3] = z;
            if (sm == 0) dpos[se] = -1;
        }
        __syncthreads();

        bf16x8 a[2][2];
        #pragma unroll
        for (int me = 0; me < 2; me++) {
            int arow = eh*32 + me*16 + l15;
            #pragma unroll
            for (int kh = 0; kh < 2; kh++)
                a[me][kh] = *(const bf16x8*)&xb[arow][((kh*4 + kgrp) ^ swz) << 3];
        }

        f32x4 y[2][2] = {{{0,0,0,0},{0,0,0,0}},{{0,0,0,0},{0,0,0,0}}};
        #pragma unroll
        for (int c = 0; c < 8; c++) {
            float4 bv[2];
            bv[0] = *(const float4*)&bts[c][eh*32 +      (kgrp << 2)];
            bv[1] = *(const float4*)&bts[c][eh*32 + 16 + (kgrp << 2)];
            bf16x8 bfr[2][2];
            #pragma unroll
            for (int nb = 0; nb < 2; nb++) {
                int brow = oh*32 + nb*16 + l15;
                #pragma unroll
                for (int kh = 0; kh < 2; kh++)
                    bfr[nb][kh] = *(const bf16x8*)&wt[c][brow][((kh*4 + kgrp) ^ swz) << 3];
            }
            #pragma unroll
            for (int me = 0; me < 2; me++) {
                #pragma unroll
                for (int nb = 0; nb < 2; nb++) {
                    f32x4 t = {0.f, 0.f, 0.f, 0.f};
                    t = __builtin_amdgcn_mfma_f32_16x16x32_bf16(a[me][0], bfr[nb][0], t, 0, 0, 0);
                    t = __builtin_amdgcn_mfma_f32_16x16x32_bf16(a[me][1], bfr[nb][1], t, 0, 0, 0);
                    y[me][nb][0] = fmaf(bv[me].x, t[0], y[me][nb][0]);
                    y[me][nb][1] = fmaf(bv[me].y, t[1], y[me][nb][1]);
                    y[me][nb][2] = fmaf(bv[me].z, t[2], y[me][nb][2]);
                    y[me][nb][3] = fmaf(bv[me].w, t[3], y[me][nb][3]);
                }
            }
        }
        #pragma unroll
        for (int me = 0; me < 2; me++) {
            #pragma unroll
            for (int r = 0; r < 4; r++) {
                int el = eh*32 + me*16 + (kgrp << 2) + r;
                int dp = dpos[el];
                if (dp >= 0) {
                    unsigned short* yp = ye + (size_t)dp*64 + oh*32 + l15;
                    yp[0]  = f2bf(y[me][0][r]);
                    yp[16] = f2bf(y[me][1][r]);
                }
            }
        }
    }
}

// ---------------- gather by dst: sequential ye rows, bf16 in/out ----------------
__global__ __launch_bounds__(256) void k_gather(
    const unsigned short* __restrict__ ye, const int* __restrict__ csr,
    const unsigned short* __restrict__ xin, const float* __restrict__ root,
    const float* __restrict__ bias, const float* __restrict__ invdeg,
    unsigned short* __restrict__ hout, int N)
{
    __shared__ float sh[4][64];
    const int w = threadIdx.x >> 6, lane = threadIdx.x & 63;
    const int n = blockIdx.x*4 + w;
    if (n >= N) return;
    const int s0 = csr[n], s1 = csr[n+1];
    const int j8 = lane >> 3, c8 = lane & 7;
    float acc[8] = {};
    for (int base = s0; base < s1; base += 8) {
        int ei = base + j8;
        if (ei < s1) {
            bf16x8 v = *(const bf16x8*)(ye + (size_t)ei*64 + c8*8);
            #pragma unroll
            for (int k = 0; k < 8; k++)
                acc[k] += bf2f((unsigned short)v[k]);
        }
    }
    #pragma unroll
    for (int m = 8; m <= 32; m <<= 1) {
        #pragma unroll
        for (int k = 0; k < 8; k++)
            acc[k] += __shfl_xor(acc[k], m, 64);
    }
    if (j8 == 0) {
        #pragma unroll
        for (int k = 0; k < 8; k++) sh[w][c8*8+k] = acc[k];
    }
    float aggr = sh[w][lane];            // same-wave LDS write->read
    float av = aggr * invdeg[n];
    float xv = bf2f(xin[(size_t)n*64 + lane]);
    float rt = bias[lane];
    #pragma unroll 8
    for (int i = 0; i < 64; i++)
        rt = fmaf(__shfl(xv, i, 64), root[i*64 + lane], rt);
    hout[(size_t)n*64 + lane] = f2bf(elu_f(av + rt));
}

// ---------------- grid-pruned exact 3-NN + interpolation (one wave per query) ----------------
__global__ __launch_bounds__(256) void k_knn_grid(
    const float4* __restrict__ px4, const float4* __restrict__ pxg,
    const int* __restrict__ gidx, const int* __restrict__ gstart,
    const float* __restrict__ gmeta, const float* __restrict__ posy,
    const int* __restrict__ by, const unsigned short* __restrict__ h2,
    float* __restrict__ out, int N, int Ny)
{
    const int q    = blockIdx.x*4 + (threadIdx.x >> 6);
    const int lane = threadIdx.x & 63;

    float offv = (float)by[q] * 1e5f;
    float qa = posy[q*3+0]+offv, qb = posy[q*3+1]+offv, qc = posy[q*3+2]+offv;
    float sy = qa*qa + qb*qb + qc*qc;
    float a2 = -2.f*qa, b2 = -2.f*qb, c2 = -2.f*qc;

    float lo0 = gmeta[0], lo1 = gmeta[1], lo2 = gmeta[2];
    float w0g = gmeta[3], w1g = gmeta[4], w2g = gmeta[5];
    float iw0 = gmeta[6], iw1 = gmeta[7], iw2 = gmeta[8];
    int cx = (int)((qa - lo0) * iw0); cx = cx < 0 ? 0 : (cx > GDIM-1 ? GDIM-1 : cx);
    int cy = (int)((qb - lo1) * iw1); cy = cy < 0 ? 0 : (cy > GDIM-1 ? GDIM-1 : cy);
    int cz = (int)((qc - lo2) * iw2); cz = cz < 0 ? 0 : (cz > GDIM-1 ? GDIM-1 : cz);

    float d0 = 3.4e38f, d1 = 3.4e38f, d2s = 3.4e38f;
    int   i0 = 0x7fffffff, i1 = 0x7fffffff, i2 = 0x7fffffff;

    // 27-cell cube, 2 lanes per cell
    int cl = lane % 27, half = lane / 27;
    bool lv = lane < 54;
    int gx = cx + cl % 3 - 1, gy = cy + (cl/3) % 3 - 1, gz = cz + cl/9 - 1;
    lv = lv && gx >= 0 && gx < GDIM && gy >= 0 && gy < GDIM && gz >= 0 && gz < GDIM;
    int cs = 0, ce = 0;
    if (lv) {
        int cid = gx + (gy << 4) + (gz << 8);
        cs = gstart[cid]; ce = gstart[cid+1];
    }
    for (int s = cs + half; s < ce; s += 2) {
        float4 p = pxg[s];
        int gi = gidx[s];
        float u = fmaf(a2, p.x, fmaf(b2, p.y, fmaf(c2, p.z, sy + p.w)));
        bool bl2 = (u < d2s) || (u == d2s && gi < i2);
        bool bl1 = (u < d1)  || (u == d1  && gi < i1);
        bool bl0 = (u < d0)  || (u == d0  && gi < i0);
        if (bl2) {
            d2s = bl1 ? d1 : u;  i2 = bl1 ? i1 : gi;
            if (bl1) {
                d1 = bl0 ? d0 : u; i1 = bl0 ? i0 : gi;
                if (bl0) { d0 = u; i0 = gi; }
            }
        }
    }
    float rd[3]; int ri[3];
    merge3(d0, i0, d1, i1, d2s, i2, rd, ri);

    // certification: margin from q to nearest face of the cube region that has cells beyond it
    float bound = 3.4e38f;
    if (cx >= 2)      bound = fminf(bound, qa - (lo0 + (float)(cx-1)*w0g));
    if (cx <= GDIM-3) bound = fminf(bound, (lo0 + (float)(cx+2)*w0g) - qa);
    if (cy >= 2)      bound = fminf(bound, qb - (lo1 + (float)(cy-1)*w1g));
    if (cy <= GDIM-3) bound = fminf(bound, (lo1 + (float)(cy+2)*w1g) - qb);
    if (cz >= 2)      bound = fminf(bound, qc - (lo2 + (float)(cz-1)*w2g));
    if (cz <= GDIM-3) bound = fminf(bound, (lo2 + (float)(cz+2)*w2g) - qc);
    bool cert = (bound > 0.f) && (rd[2] < bound*bound);

    if (!cert) {   // exact fallback: full brute scan (wave-parallel)
        d0 = d1 = d2s = 3.4e38f;
        i0 = i1 = i2 = 0x7fffffff;
        for (int p = lane; p < N; p += 64) {
            float4 pp = px4[p];
            float u = fmaf(a2, pp.x, fmaf(b2, pp.y, fmaf(c2, pp.z, sy + pp.w)));
            bool bl2 = (u < d2s) || (u == d2s && p < i2);
            bool bl1 = (u < d1)  || (u == d1  && p < i1);
            bool bl0 = (u < d0)  || (u == d0  && p < i0);
            if (bl2) {
                d2s = bl1 ? d1 : u;  i2 = bl1 ? i1 : p;
                if (bl1) {
                    d1 = bl0 ? d0 : u; i1 = bl0 ? i0 : p;
                    if (bl0) { d0 = u; i0 = p; }
                }
            }
        }
        merge3(d0, i0, d1, i1, d2s, i2, rd, ri);
    }

    float ww0 = 1.f/fmaxf(rd[0], 1e-16f);
    float ww1 = 1.f/fmaxf(rd[1], 1e-16f);
    float ww2 = 1.f/fmaxf(rd[2], 1e-16f);
    float wsum = ww0 + ww1 + ww2;
    float v = ww0*bf2f(h2[(size_t)ri[0]*64 + lane])
            + ww1*bf2f(h2[(size_t)ri[1]*64 + lane])
            + ww2*bf2f(h2[(size_t)ri[2]*64 + lane]);
    out[(size_t)q*64 + lane] = v / wsum;
}

extern "C" void kernel_launch(void* const* d_in, const int* in_sizes, int n_in,
                              void* d_out, int out_size, void* d_ws, size_t ws_size,
                              hipStream_t stream)
{
    const float* x     = (const float*)d_in[0];
    const int*   ei    = (const int*)d_in[1];
    const float* ea    = (const float*)d_in[2];
    const float* posx  = (const float*)d_in[3];
    const int*   bx    = (const int*)d_in[4];
    const float* posy  = (const float*)d_in[5];
    const int*   by    = (const int*)d_in[6];
    const float* Wa    = (const float*)d_in[7];
    const float* roota = (const float*)d_in[8];
    const float* biasa = (const float*)d_in[9];
    const float* Wb    = (const float*)d_in[10];
    const float* rootb = (const float*)d_in[11];
    const float* biasb = (const float*)d_in[12];

    const int N  = in_sizes[0] / 64;
    const int E  = in_sizes[1] / 2;
    const int Ny = in_sizes[5] / 3;
    const int* srcp = ei;
    const int* dstp = ei + E;

    char* ws = (char*)d_ws;
    size_t off = 0;
    auto alloc = [&](size_t bytes) { void* p = ws + off; off += (bytes + 255) & ~255ull; return p; };
    float*  basis    = (float*)alloc((size_t)E*8*4);
    int*    cellid   = (int*)  alloc((size_t)E*4);
    int*    rank     = (int*)  alloc((size_t)E*4);
    int*    elist    = (int*)  alloc((size_t)E*4);
    int*    dstpos   = (int*)  alloc((size_t)E*4);
    int*    deg      = (int*)  alloc((size_t)N*4);     // deg+cellcnt+mmax contiguous: one zero memset
    int*    cellcnt  = (int*)  alloc(64*4);
    unsigned int* mmax = (unsigned int*)alloc(3*4);
    unsigned int* mmin = (unsigned int*)alloc(3*4);    // 0xFF memset
    int*    csr      = (int*)  alloc((size_t)(N+1)*4);
    float*  invdeg   = (float*)alloc((size_t)N*4);
    int*    cellstart= (int*)  alloc(65*4);
    int*    cellfill = (int*)  alloc(64*4);
    int*    gstart   = (int*)  alloc(4097*4);
    int*    gfill    = (int*)  alloc(4096*4);
    float*  gmeta    = (float*)alloc(16*4);
    unsigned short* xbf = (unsigned short*)alloc((size_t)N*64*2);
    unsigned short* h1  = (unsigned short*)alloc((size_t)N*64*2);
    unsigned short* h2  = (unsigned short*)alloc((size_t)N*64*2);
    float4* px4      = (float4*)alloc((size_t)N*16);
    float4* pxg      = (float4*)alloc((size_t)N*16);
    int*    gidx     = (int*)  alloc((size_t)N*4);
    unsigned short* WTa = (unsigned short*)alloc((size_t)125*4096*2);
    unsigned short* WTb = (unsigned short*)alloc((size_t)125*4096*2);
    unsigned short* ye  = (unsigned short*)alloc((size_t)E*64*2);
    (void)ws_size; (void)n_in; (void)out_size;

    const int EB  = CDIV(E,256);       // 512
    const int PB  = CDIV(N,256);       // 32
    const int XB  = CDIV(N*8,256);     // 256 (x->bf16, 8 elems/thread)
    const int PXB = CDIV(N,256);       // 32 (knn point scatter)

    // zero: deg (N*4) + cellcnt (256B slot) + mmax (256B slot); then mmin = 0xFF
    hipMemsetAsync(deg, 0, (size_t)N*4 + 256 + 256, stream);
    hipMemsetAsync(mmin, 0xFF, 12, stream);

    k_basis_px<<<EB+PB+XB, 256, 0, stream>>>(ea, dstp, basis, cellid, cellcnt, deg, rank,
                                             E, EB, PB, posx, bx, px4, N, x, xbf, mmin, mmax);
    k_degscan <<<1, 1024, 0, stream>>>(deg, csr, invdeg, N, cellcnt, cellstart, cellfill,
                                       px4, mmin, mmax, gstart, gfill, gmeta);
    k_pack    <<<2*EB + 250 + PXB, 256, 0, stream>>>(cellid, cellfill, elist, dstp, rank,
                                               csr, dstpos, E, EB, Wa, Wb, WTa, WTb,
                                               px4, gmeta, gfill, pxg, gidx, N);

    k_conv  <<<64*WPCV, 256, 0, stream>>>(xbf, WTa, elist, cellstart, basis, srcp, dstpos, ye);
    k_gather<<<CDIV(N,4), 256, 0, stream>>>(ye, csr, xbf, roota, biasa, invdeg, h1, N);

    k_conv  <<<64*WPCV, 256, 0, stream>>>(h1, WTb, elist, cellstart, basis, srcp, dstpos, ye);
    k_gather<<<CDIV(N,4), 256, 0, stream>>>(ye, csr, h1, rootb, biasb, invdeg, h2, N);

    k_knn_grid<<<Ny/4, 256, 0, stream>>>(px4, pxg, gidx, gstart, gmeta, posy, by, h2,
                                         (float*)d_out, N, Ny);
}

// Round 14
// 165.183 us; speedup vs baseline: 1.2546x; 1.1843x over previous
//
#include <hip/hip_runtime.h>
#include <hip/hip_bf16.h>
#include <math.h>

#define CDIV(a,b) (((a)+(b)-1)/(b))
#define WPCV 8    // workgroups per cell for conv (64*8 = 512 blocks)
#define KCH 32    // point chunks for knn (16 per fused gather dispatch)

typedef __attribute__((ext_vector_type(8))) short bf16x8;
typedef __attribute__((ext_vector_type(4))) float f32x4;

__device__ __forceinline__ float elu_f(float x){ return x > 0.f ? x : expm1f(x); }
__device__ __forceinline__ unsigned short f2bf(float x){
    __hip_bfloat16 h = __float2bfloat16(x);
    union { __hip_bfloat16 b; unsigned short u; } cv; cv.b = h; return cv.u;
}
__device__ __forceinline__ float bf2f(unsigned short u){
    unsigned int ui = ((unsigned int)u) << 16;
    union { unsigned int u; float f; } cv; cv.u = ui; return cv.f;
}

// ---------------- fused: basis/hist/deg/rank + pos_x preprocess + x->bf16 ----------------
__global__ void k_basis_px(const float* __restrict__ ea, const int* __restrict__ dst,
                        float* __restrict__ basis, int* __restrict__ cellid,
                        int* __restrict__ cellcnt, int* __restrict__ deg,
                        int* __restrict__ rank, int E, int EB, int PB,
                        const float* __restrict__ posx, const int* __restrict__ bx,
                        float4* __restrict__ px4, int N,
                        const float* __restrict__ x, unsigned short* __restrict__ xbf)
{
    const int tid = threadIdx.x;
    const int bid = blockIdx.x;
    if (bid >= EB) {
        int r = bid - EB;
        if (r < PB) {                      // ---- px part ----
            int n = r*256 + tid;
            if (n < N) {
                float off = (float)bx[n] * 1e5f;
                float a = posx[n*3+0]+off, b = posx[n*3+1]+off, c = posx[n*3+2]+off;
                px4[n] = make_float4(a, b, c, a*a + b*b + c*c);
            }
        } else {                           // ---- x -> bf16 (8 elems/thread) ----
            int i = (r - PB)*256 + tid;
            if (i < N*8) {
                const float4* xs = (const float4*)x + (size_t)i*2;
                float4 a4 = xs[0], b4 = xs[1];
                bf16x8 v;
                v[0]=(short)f2bf(a4.x); v[1]=(short)f2bf(a4.y);
                v[2]=(short)f2bf(a4.z); v[3]=(short)f2bf(a4.w);
                v[4]=(short)f2bf(b4.x); v[5]=(short)f2bf(b4.y);
                v[6]=(short)f2bf(b4.z); v[7]=(short)f2bf(b4.w);
                *(bf16x8*)(xbf + (size_t)i*8) = v;
            }
        }
        return;
    }
    // ---- basis part ----
    __shared__ int hist[64];
    if (tid < 64) hist[tid] = 0;
    __syncthreads();
    int e = bid * 256 + tid;
    if (e < E) {
        float f[3]; int bi[3];
        #pragma unroll
        for (int d = 0; d < 3; d++) {
            float v = ea[e*3+d] * 4.f;      // K-1 = 4
            float b = floorf(v);
            f[d] = v - b;
            int bb = (int)b; bb = bb < 0 ? 0 : (bb > 3 ? 3 : bb);
            bi[d] = bb;
        }
        int cell = bi[0] + 4*bi[1] + 16*bi[2];
        cellid[e] = cell;
        atomicAdd(&hist[cell], 1);
        rank[e] = atomicAdd(deg + dst[e], 1);
        float bs[8];
        #pragma unroll
        for (int c = 0; c < 8; c++) {
            float b = 1.f;
            #pragma unroll
            for (int d = 0; d < 3; d++)
                b *= ((c>>d)&1) ? f[d] : (1.f - f[d]);
            bs[c] = b;
        }
        float4* bw = (float4*)(basis + (size_t)e*8);
        bw[0] = make_float4(bs[0],bs[1],bs[2],bs[3]);
        bw[1] = make_float4(bs[4],bs[5],bs[6],bs[7]);
    }
    __syncthreads();
    if (tid < 64 && hist[tid]) atomicAdd(cellcnt + tid, hist[tid]);
}

// ---------------- degree prefix scan (one block) + invdeg + cell scan ----------------
__global__ __launch_bounds__(1024) void k_degscan(const int* __restrict__ deg,
                        int* __restrict__ csr, float* __restrict__ invdeg, int N,
                        const int* __restrict__ cellcnt, int* __restrict__ cellstart,
                        int* __restrict__ cellfill)
{
    __shared__ int buf[2][1024];
    const int t = threadIdx.x;
    if (t < 64) {                          // 64-cell prefix scan in wave 0
        int v = cellcnt[t];
        int s = v;
        #pragma unroll
        for (int off = 1; off < 64; off <<= 1) {
            int o = __shfl_up(s, off, 64);
            if (t >= off) s += o;
        }
        cellstart[t] = s - v; cellfill[t] = s - v;
        if (t == 63) cellstart[64] = s;
    }
    const int base = t*8;
    int loc[8]; int s = 0;
    #pragma unroll
    for (int j = 0; j < 8; j++) {
        loc[j] = s;
        int d = (base+j < N) ? deg[base+j] : 0;
        if (base+j < N) invdeg[base+j] = 1.f / fmaxf((float)d, 1.f);
        s += d;
    }
    buf[0][t] = s; __syncthreads();
    int pb = 0;
    for (int off = 1; off < 1024; off <<= 1) {
        int v = buf[pb][t];
        if (t >= off) v += buf[pb][t-off];
        buf[pb^1][t] = v; __syncthreads(); pb ^= 1;
    }
    int excl = buf[pb][t] - s;
    #pragma unroll
    for (int j = 0; j < 8; j++)
        if (base+j < N) csr[base+j] = excl + loc[j];
    if (t == 0) csr[N] = buf[pb][1023];
}

// ---------------- fused: scatter + dstpos + wprep ----------------
__global__ __launch_bounds__(256) void k_pack(
    const int* __restrict__ cellid, int* __restrict__ fill, int* __restrict__ elist,
    const int* __restrict__ dst, const int* __restrict__ rank,
    const int* __restrict__ csr, int* __restrict__ dstpos, int E, int SB,
    const float* __restrict__ Wa, const float* __restrict__ Wb,
    unsigned short* __restrict__ WTa, unsigned short* __restrict__ WTb)
{
    __shared__ float shbuf[64*65];
    const int tid = threadIdx.x;
    const int bid = blockIdx.x;
    if (bid < SB) {                        // ---- scatter ----
        int* hist = (int*)shbuf;
        int* bas  = hist + 64;
        if (tid < 64) hist[tid] = 0;
        __syncthreads();
        int e = bid * 256 + tid;
        int cell = 0, loc = 0;
        bool act = e < E;
        if (act) { cell = cellid[e]; loc = atomicAdd(&hist[cell], 1); }
        __syncthreads();
        if (tid < 64) bas[tid] = hist[tid] ? atomicAdd(fill + tid, hist[tid]) : 0;
        __syncthreads();
        if (act) elist[bas[cell] + loc] = e;
    } else if (bid < 2*SB) {               // ---- dstpos: e -> slot in dst-sorted order ----
        int e = (bid - SB) * 256 + tid;
        if (e < E) dstpos[e] = csr[dst[e]] + rank[e];
    } else {                               // ---- wprep ----
        int b = bid - 2*SB;
        float (*ws65)[65] = (float(*)[65])shbuf;
        const float* Wsrc = (b < 125) ? (Wa + (size_t)b*4096) : (Wb + (size_t)(b-125)*4096);
        unsigned short* Wdst = (b < 125) ? (WTa + (size_t)b*4096) : (WTb + (size_t)(b-125)*4096);
        #pragma unroll
        for (int j = 0; j < 16; j++) {
            int idx = j*256 + tid;             // idx = i*64 + o
            ws65[idx>>6][idx&63] = Wsrc[idx];
        }
        __syncthreads();
        #pragma unroll
        for (int j = 0; j < 16; j++) {
            int idx = j*256 + tid;             // idx = o*64 + i
            int o = idx>>6, i = idx&63;
            Wdst[idx] = f2bf(ws65[i][o]);
        }
    }
}

// ---------------- spline conv: MFMA, W8 in LDS, bf16 input, ye dst-sorted ----------------
__global__ __launch_bounds__(256) void k_conv(
    const unsigned short* __restrict__ xin, const unsigned short* __restrict__ WT,
    const int* __restrict__ elist, const int* __restrict__ cellstart,
    const float* __restrict__ basis, const int* __restrict__ src,
    const int* __restrict__ dstpos, unsigned short* __restrict__ ye)
{
    __shared__ unsigned short wt[8][64][64];   // [corner][out][in] bf16, row-swizzled
    __shared__ unsigned short xb[64][64];      // [edge][in] bf16, row-swizzled
    __shared__ float bts[8][64];               // [corner][edge]
    __shared__ int dpos[64];

    const int cell = blockIdx.x / WPCV;
    const int sub  = blockIdx.x % WPCV;
    const int tid  = threadIdx.x;
    const int w    = tid >> 6;
    const int lane = tid & 63;
    const int eh   = w >> 1;       // edge half (0/1)
    const int oh   = w & 1;        // out half (0/1)
    const int l15  = lane & 15;
    const int kgrp = lane >> 4;    // 0..3
    const int swz  = lane & 7;

    int kc[8];
    {
        int b0 = cell & 3, b1 = (cell >> 2) & 3, b2 = (cell >> 4) & 3;
        #pragma unroll
        for (int c = 0; c < 8; c++)
            kc[c] = (b0 + (c&1)) + 5*(b1 + ((c>>1)&1)) + 25*(b2 + ((c>>2)&1));
    }

    #pragma unroll
    for (int j = 0; j < 16; j++) {
        int cj  = j >> 1;
        int off = ((j & 1) << 8) + tid;
        int row = off >> 3, colc = off & 7;
        bf16x8 v = ((const bf16x8*)(WT + (size_t)kc[cj]*4096))[off];
        *(bf16x8*)&wt[cj][row][(colc ^ (row & 7)) << 3] = v;
    }

    const int s0 = cellstart[cell], s1 = cellstart[cell+1];
    const int se = tid >> 2, sm = tid & 3;

    for (int base = s0 + sub*64; base < s1; base += WPCV*64) {
        int ne = s1 - base; ne = ne > 64 ? 64 : ne;
        __syncthreads();
        int c0 = (sm*2)     ^ (se & 7);
        int c1 = (sm*2 + 1) ^ (se & 7);
        if (se < ne) {
            int eid = elist[base + se];
            int sn  = src[eid];
            const bf16x8* xr = (const bf16x8*)(xin + (size_t)sn*64);
            bf16x8 v0 = xr[sm*2], v1 = xr[sm*2+1];
            *(bf16x8*)&xb[se][c0 << 3] = v0;
            *(bf16x8*)&xb[se][c1 << 3] = v1;
            if (sm == 0) {
                const float4* br = (const float4*)(basis + (size_t)eid*8);
                float4 bA = br[0], bB = br[1];
                bts[0][se]=bA.x; bts[1][se]=bA.y; bts[2][se]=bA.z; bts[3][se]=bA.w;
                bts[4][se]=bB.x; bts[5][se]=bB.y; bts[6][se]=bB.z; bts[7][se]=bB.w;
                dpos[se] = dstpos[eid];
            }
        } else {
            bf16x8 z = {0,0,0,0,0,0,0,0};
            *(bf16x8*)&xb[se][c0 << 3] = z;
            *(bf16x8*)&xb[se][c1 << 3] = z;
            if (sm == 0) dpos[se] = -1;
        }
        __syncthreads();

        bf16x8 a[2][2];
        #pragma unroll
        for (int me = 0; me < 2; me++) {
            int arow = eh*32 + me*16 + l15;
            #pragma unroll
            for (int kh = 0; kh < 2; kh++)
                a[me][kh] = *(const bf16x8*)&xb[arow][((kh*4 + kgrp) ^ swz) << 3];
        }

        f32x4 y[2][2] = {{{0,0,0,0},{0,0,0,0}},{{0,0,0,0},{0,0,0,0}}};
        #pragma unroll
        for (int c = 0; c < 8; c++) {
            float4 bv[2];
            bv[0] = *(const float4*)&bts[c][eh*32 +      (kgrp << 2)];
            bv[1] = *(const float4*)&bts[c][eh*32 + 16 + (kgrp << 2)];
            bf16x8 bfr[2][2];
            #pragma unroll
            for (int nb = 0; nb < 2; nb++) {
                int brow = oh*32 + nb*16 + l15;
                #pragma unroll
                for (int kh = 0; kh < 2; kh++)
                    bfr[nb][kh] = *(const bf16x8*)&wt[c][brow][((kh*4 + kgrp) ^ swz) << 3];
            }
            #pragma unroll
            for (int me = 0; me < 2; me++) {
                #pragma unroll
                for (int nb = 0; nb < 2; nb++) {
                    f32x4 t = {0.f, 0.f, 0.f, 0.f};
                    t = __builtin_amdgcn_mfma_f32_16x16x32_bf16(a[me][0], bfr[nb][0], t, 0, 0, 0);
                    t = __builtin_amdgcn_mfma_f32_16x16x32_bf16(a[me][1], bfr[nb][1], t, 0, 0, 0);
                    y[me][nb][0] = fmaf(bv[me].x, t[0], y[me][nb][0]);
                    y[me][nb][1] = fmaf(bv[me].y, t[1], y[me][nb][1]);
                    y[me][nb][2] = fmaf(bv[me].z, t[2], y[me][nb][2]);
                    y[me][nb][3] = fmaf(bv[me].w, t[3], y[me][nb][3]);
                }
            }
        }
        #pragma unroll
        for (int me = 0; me < 2; me++) {
            #pragma unroll
            for (int r = 0; r < 4; r++) {
                int el = eh*32 + me*16 + (kgrp << 2) + r;
                int dp = dpos[el];
                if (dp >= 0) {
                    unsigned short* yp = ye + (size_t)dp*64 + oh*32 + l15;
                    yp[0]  = f2bf(y[me][0][r]);
                    yp[16] = f2bf(y[me][1][r]);
                }
            }
        }
    }
}

// ---------------- fused: gather (mean+root+bias+ELU) + knn_part half ----------------
// blocks [0, KB): knn chunks [chbase, chbase+16); blocks [KB, KB+GB): gather.
// knn blocks first = long-running; gather blocks backfill CU capacity.
__global__ __launch_bounds__(256) void k_gather_knn(
    const unsigned short* __restrict__ ye, const int* __restrict__ csr,
    const unsigned short* __restrict__ xin, const float* __restrict__ root,
    const float* __restrict__ bias, const float* __restrict__ invdeg,
    unsigned short* __restrict__ hout, int N, int KB,
    const float4* __restrict__ px4, const float* __restrict__ posy,
    const int* __restrict__ by, float* __restrict__ pd, int* __restrict__ pi,
    int Npts, int Ny, int chbase)
{
    __shared__ float sh[4][64];
    const int bid = blockIdx.x;
    const int tid = threadIdx.x;

    if (bid < KB) {
        // ---- knn_part (round-8 proven body, scalar point loads) ----
        const int qb  = (bid / 16) * 256;
        const int ch  = chbase + (bid % 16);
        const int NC  = Npts / KCH;            // 256
        const int q = qb + tid;
        float off = (float)by[q] * 1e5f;
        float qa = posy[q*3+0]+off, qbv = posy[q*3+1]+off, qc = posy[q*3+2]+off;
        float sy = qa*qa + qbv*qbv + qc*qc;
        float qa2 = -2.f*qa, qb2 = -2.f*qbv, qc2 = -2.f*qc;

        const float4* __restrict__ pts = px4 + (size_t)ch * NC;
        const int gbase = ch * NC;

        float d0 = 3.4e38f, d1 = 3.4e38f, d2s = 3.4e38f;
        int   i0 = 0x7fffffff, i1 = 0x7fffffff, i2 = 0x7fffffff;
        #pragma unroll 16
        for (int p = 0; p < NC; p++) {
            float4 pt = pts[p];                  // uniform -> scalar load
            float u  = fmaf(qa2, pt.x, fmaf(qb2, pt.y, fmaf(qc2, pt.z, sy + pt.w)));
            int   gi = gbase + p;
            bool c0 = u < d0, c1 = u < d1, c2 = u < d2s;
            float nd0 = fminf(d0, u);
            float nd1 = __builtin_amdgcn_fmed3f(d0, u, d1);
            float nd2 = __builtin_amdgcn_fmed3f(u, d1, d2s);
            i2 = c1 ? i1 : (c2 ? gi : i2);       // uses old i1
            i1 = c0 ? i0 : (c1 ? gi : i1);       // uses old i0
            i0 = c0 ? gi : i0;
            d0 = nd0; d1 = nd1; d2s = nd2;
        }
        size_t ob = ((size_t)ch*Ny + q)*3;
        pd[ob+0]=d0; pd[ob+1]=d1; pd[ob+2]=d2s;
        pi[ob+0]=i0; pi[ob+1]=i1; pi[ob+2]=i2;
        return;
    }

    // ---- gather ----
    const int w = tid >> 6, lane = tid & 63;
    const int n = (bid - KB)*4 + w;
    if (n >= N) return;
    const int s0 = csr[n], s1 = csr[n+1];
    const int j8 = lane >> 3, c8 = lane & 7;
    float acc[8] = {};
    for (int base = s0; base < s1; base += 8) {
        int ei = base + j8;
        if (ei < s1) {
            bf16x8 v = *(const bf16x8*)(ye + (size_t)ei*64 + c8*8);
            #pragma unroll
            for (int k = 0; k < 8; k++)
                acc[k] += bf2f((unsigned short)v[k]);
        }
    }
    #pragma unroll
    for (int m = 8; m <= 32; m <<= 1) {
        #pragma unroll
        for (int k = 0; k < 8; k++)
            acc[k] += __shfl_xor(acc[k], m, 64);
    }
    if (j8 == 0) {
        #pragma unroll
        for (int k = 0; k < 8; k++) sh[w][c8*8+k] = acc[k];
    }
    float aggr = sh[w][lane];            // same-wave LDS write->read
    float av = aggr * invdeg[n];
    float xv = bf2f(xin[(size_t)n*64 + lane]);
    float rt = bias[lane];
    #pragma unroll 8
    for (int i = 0; i < 64; i++)
        rt = fmaf(__shfl(xv, i, 64), root[i*64 + lane], rt);
    hout[(size_t)n*64 + lane] = f2bf(elu_f(av + rt));
}

// ---------------- 3-NN merge: 96 candidates + interpolate (bf16 h2) ----------------
__global__ __launch_bounds__(256) void k_knn_merge(
    const float* __restrict__ pd, const int* __restrict__ pi,
    const unsigned short* __restrict__ h2, float* __restrict__ out, int Ny)
{
    const int w = threadIdx.x >> 6, lane = threadIdx.x & 63;
    const int q = blockIdx.x*4 + w;
    float a0 = 3.4e38f, a1 = 3.4e38f, a2 = 3.4e38f;
    int   b0 = 0x7fffffff, b1 = 0x7fffffff, b2 = 0x7fffffff;
    if (lane < KCH) {
        size_t base = ((size_t)lane*Ny + q)*3;
        a0 = pd[base+0]; a1 = pd[base+1]; a2 = pd[base+2];
        b0 = pi[base+0]; b1 = pi[base+1]; b2 = pi[base+2];
    }
    float rd[3]; int ri[3];
    #pragma unroll
    for (int j = 0; j < 3; j++) {
        float md = a0; int mi = b0;
        #pragma unroll
        for (int s = 1; s < 64; s <<= 1) {
            float od = __shfl_xor(md, s, 64);
            int   oi = __shfl_xor(mi, s, 64);
            if (od < md || (od == md && oi < mi)) { md = od; mi = oi; }
        }
        rd[j] = md; ri[j] = mi;
        if (b0 == mi) { a0=a1; b0=b1; a1=a2; b1=b2; a2=3.4e38f; b2=0x7fffffff; }
    }
    float w0 = 1.f/fmaxf(rd[0], 1e-16f);
    float w1 = 1.f/fmaxf(rd[1], 1e-16f);
    float w2 = 1.f/fmaxf(rd[2], 1e-16f);
    float ws = w0 + w1 + w2;
    float v = w0*bf2f(h2[(size_t)ri[0]*64+lane]) + w1*bf2f(h2[(size_t)ri[1]*64+lane])
            + w2*bf2f(h2[(size_t)ri[2]*64+lane]);
    out[(size_t)q*64+lane] = v / ws;
}

extern "C" void kernel_launch(void* const* d_in, const int* in_sizes, int n_in,
                              void* d_out, int out_size, void* d_ws, size_t ws_size,
                              hipStream_t stream)
{
    const float* x     = (const float*)d_in[0];
    const int*   ei    = (const int*)d_in[1];
    const float* ea    = (const float*)d_in[2];
    const float* posx  = (const float*)d_in[3];
    const int*   bx    = (const int*)d_in[4];
    const float* posy  = (const float*)d_in[5];
    const int*   by    = (const int*)d_in[6];
    const float* Wa    = (const float*)d_in[7];
    const float* roota = (const float*)d_in[8];
    const float* biasa = (const float*)d_in[9];
    const float* Wb    = (const float*)d_in[10];
    const float* rootb = (const float*)d_in[11];
    const float* biasb = (const float*)d_in[12];

    const int N  = in_sizes[0] / 64;
    const int E  = in_sizes[1] / 2;
    const int Ny = in_sizes[5] / 3;
    const int* srcp = ei;
    const int* dstp = ei + E;

    char* ws = (char*)d_ws;
    size_t off = 0;
    auto alloc = [&](size_t bytes) { void* p = ws + off; off += (bytes + 255) & ~255ull; return p; };
    float*  basis    = (float*)alloc((size_t)E*8*4);
    int*    cellid   = (int*)  alloc((size_t)E*4);
    int*    rank     = (int*)  alloc((size_t)E*4);
    int*    elist    = (int*)  alloc((size_t)E*4);
    int*    dstpos   = (int*)  alloc((size_t)E*4);
    int*    deg      = (int*)  alloc((size_t)N*4);     // deg + cellcnt contiguous: one memset
    int*    cellcnt  = (int*)  alloc(64*4);
    int*    csr      = (int*)  alloc((size_t)(N+1)*4);
    float*  invdeg   = (float*)alloc((size_t)N*4);
    int*    cellstart= (int*)  alloc(65*4);
    int*    cellfill = (int*)  alloc(64*4);
    unsigned short* xbf = (unsigned short*)alloc((size_t)N*64*2);
    unsigned short* h1  = (unsigned short*)alloc((size_t)N*64*2);
    unsigned short* h2  = (unsigned short*)alloc((size_t)N*64*2);
    float4* px4      = (float4*)alloc((size_t)N*16);
    unsigned short* WTa = (unsigned short*)alloc((size_t)125*4096*2);
    unsigned short* WTb = (unsigned short*)alloc((size_t)125*4096*2);
    unsigned short* ye  = (unsigned short*)alloc((size_t)E*64*2);
    float* pd = (float*)alloc((size_t)Ny*KCH*3*4);   // no aliasing: gather reads ye concurrently
    int*   pi = (int*)  alloc((size_t)Ny*KCH*3*4);
    (void)ws_size; (void)n_in; (void)out_size;

    const int EB = CDIV(E,256);        // 512
    const int PB = CDIV(N,256);        // 32
    const int XB = CDIV(N*8,256);      // 256 (x->bf16, 8 elems/thread)
    const int GB = CDIV(N,4);          // 2048 gather blocks
    const int KB = (Ny/256)*16;        // 1024 knn blocks per half

    hipMemsetAsync(deg, 0, (size_t)N*4 + 256, stream);   // zeroes deg + cellcnt

    k_basis_px<<<EB+PB+XB, 256, 0, stream>>>(ea, dstp, basis, cellid, cellcnt, deg, rank,
                                             E, EB, PB, posx, bx, px4, N, x, xbf);
    k_degscan <<<1, 1024, 0, stream>>>(deg, csr, invdeg, N, cellcnt, cellstart, cellfill);
    k_pack    <<<2*EB + 250, 256, 0, stream>>>(cellid, cellfill, elist, dstp, rank,
                                               csr, dstpos, E, EB, Wa, Wb, WTa, WTb);

    k_conv      <<<64*WPCV, 256, 0, stream>>>(xbf, WTa, elist, cellstart, basis, srcp, dstpos, ye);
    k_gather_knn<<<KB+GB, 256, 0, stream>>>(ye, csr, xbf, roota, biasa, invdeg, h1, N, KB,
                                            px4, posy, by, pd, pi, N, Ny, 0);

    k_conv      <<<64*WPCV, 256, 0, stream>>>(h1, WTb, elist, cellstart, basis, srcp, dstpos, ye);
    k_gather_knn<<<KB+GB, 256, 0, stream>>>(ye, csr, h1, rootb, biasb, invdeg, h2, N, KB,
                                            px4, posy, by, pd, pi, N, Ny, 16);

    k_knn_merge<<<Ny/4, 256, 0, stream>>>(pd, pi, h2, (float*)d_out, Ny);
}